// Round 7
// baseline (604.627 us; speedup 1.0000x reference)
//
#include <hip/hip_runtime.h>

#define NN 20000   // nodes per graph

typedef __attribute__((ext_vector_type(8))) __bf16 bf16x8;
typedef __attribute__((ext_vector_type(4))) float f32x4;

__device__ __forceinline__ unsigned short f2bf(float f) {
    unsigned u = __builtin_bit_cast(unsigned, f);
    u += 0x7fff + ((u >> 16) & 1);   // round-to-nearest-even
    return (unsigned short)(u >> 16);
}
__device__ __forceinline__ float bf2f(unsigned short h) {
    unsigned u = ((unsigned)h) << 16;
    return __builtin_bit_cast(float, u);
}

// ---------------- CSR build ----------------

__global__ void k_count(const int* __restrict__ dst, long dst_bs,
                        int* __restrict__ counts, long cnt_bs, int E) {
    int b = blockIdx.z;
    const int* d = dst + (size_t)b * dst_bs;
    int* c = counts + (size_t)b * cnt_bs;
    for (int e = blockIdx.x * blockDim.x + threadIdx.x; e < E; e += gridDim.x * blockDim.x)
        atomicAdd(&c[d[e]], 1);
}

// one 1024-thread block per batch: exclusive scan of counts -> offs, cursor
__global__ void k_scan(const int* __restrict__ counts, long cnt_bs,
                       int* __restrict__ offs, long off_bs,
                       int* __restrict__ cursor, long cur_bs, int n) {
    int b = blockIdx.z;
    const int* cnt = counts + (size_t)b * cnt_bs;
    int* off = offs + (size_t)b * off_bs;
    int* cur = cursor + (size_t)b * cur_bs;
    __shared__ int sums[1024];
    int t = threadIdx.x;
    int chunk = (n + 1023) / 1024;
    int lo = t * chunk;
    int hi = min(lo + chunk, n);
    int s = 0;
    for (int i = lo; i < hi; i++) s += cnt[i];
    sums[t] = s;
    __syncthreads();
    for (int d2 = 1; d2 < 1024; d2 <<= 1) {
        int x = (t >= d2) ? sums[t - d2] : 0;
        __syncthreads();
        sums[t] += x;
        __syncthreads();
    }
    if (t == 1023) off[n] = sums[1023];
    int run = sums[t] - s;
    for (int i = lo; i < hi; i++) {
        int c = cnt[i];
        off[i] = run;
        cur[i] = run;
        run += c;
    }
}

__global__ void k_fill(const int* __restrict__ src, long src_bs,
                       const int* __restrict__ dst, long dst_bs,
                       int* __restrict__ cursor, long cur_bs,
                       int* __restrict__ elist, long el_bs, int E) {
    int b = blockIdx.z;
    const int* s = src + (size_t)b * src_bs;
    const int* d = dst + (size_t)b * dst_bs;
    int* cur = cursor + (size_t)b * cur_bs;
    int* el = elist + (size_t)b * el_bs;
    for (int e = blockIdx.x * blockDim.x + threadIdx.x; e < E; e += gridDim.x * blockDim.x) {
        int p = atomicAdd(&cur[d[e]], 1);
        el[p] = s[e];
    }
}

// ---------------- aggregation (fp32 src): 32-col strips, 8-lane groups, 4-edge unroll ----
// grid = (N/32, 4 passes, nb). Per-pass source strip = 2.56 MB.
// 64 KB dummy LDS caps residency at 2 blocks/CU (512 blocks < 625 blocks/strip)
// so at most ~one strip is live per XCD L2 at a time.

template <bool SPLIT>
__global__ void k_aggs(const float* __restrict__ feat, long feat_bs,
                       const int* __restrict__ offs, long off_bs,
                       const int* __restrict__ elist, long el_bs,
                       const float* __restrict__ bias,   // nullable
                       void* __restrict__ o1, void* __restrict__ o2,
                       long out_bs, int N) {
    __shared__ int ldspad[16384];    // 64 KB occupancy cap
    if (N < 0) {                     // never at runtime; keeps the allocation
        volatile int* vp = ldspad;
        vp[threadIdx.x] = (int)off_bs;
        if (vp[0] == 42) return;
    }
    int b = blockIdx.z, pass = blockIdx.y;
    int g = threadIdx.x >> 3;        // 32 groups per 256-block
    int lane = threadIdx.x & 7;      // 8 lanes * float4 = 32 cols
    int n = blockIdx.x * 32 + g;
    if (n >= N) return;
    int col0 = pass * 32 + lane * 4;
    const float* fp = feat + (size_t)b * feat_bs + col0;
    const int* off = offs + (size_t)b * off_bs;
    const int* el = elist + (size_t)b * el_bs;
    int lo = off[n], hi = off[n + 1];
    float4 a0 = make_float4(0.f, 0.f, 0.f, 0.f);
    float4 a1 = make_float4(0.f, 0.f, 0.f, 0.f);
    float4 a2 = make_float4(0.f, 0.f, 0.f, 0.f);
    float4 a3 = make_float4(0.f, 0.f, 0.f, 0.f);
    int e = lo;
    for (; e < hi && (e & 3); e++) {
        float4 v = *(const float4*)&fp[(size_t)el[e] * 128];
        a0.x += v.x; a0.y += v.y; a0.z += v.z; a0.w += v.w;
    }
    for (; e + 4 <= hi; e += 4) {
        int4 idx = *(const int4*)&el[e];
        float4 v0 = *(const float4*)&fp[(size_t)idx.x * 128];
        float4 v1 = *(const float4*)&fp[(size_t)idx.y * 128];
        float4 v2 = *(const float4*)&fp[(size_t)idx.z * 128];
        float4 v3 = *(const float4*)&fp[(size_t)idx.w * 128];
        a0.x += v0.x; a0.y += v0.y; a0.z += v0.z; a0.w += v0.w;
        a1.x += v1.x; a1.y += v1.y; a1.z += v1.z; a1.w += v1.w;
        a2.x += v2.x; a2.y += v2.y; a2.z += v2.z; a2.w += v2.w;
        a3.x += v3.x; a3.y += v3.y; a3.z += v3.z; a3.w += v3.w;
    }
    for (; e < hi; e++) {
        float4 v = *(const float4*)&fp[(size_t)el[e] * 128];
        a0.x += v.x; a0.y += v.y; a0.z += v.z; a0.w += v.w;
    }
    float4 r;
    r.x = (a0.x + a1.x) + (a2.x + a3.x);
    r.y = (a0.y + a1.y) + (a2.y + a3.y);
    r.z = (a0.z + a1.z) + (a2.z + a3.z);
    r.w = (a0.w + a1.w) + (a2.w + a3.w);
    if (bias) {
        float4 bv = *(const float4*)&bias[col0];
        r.x += bv.x; r.y += bv.y; r.z += bv.z; r.w += bv.w;
    }
    size_t oi = (size_t)b * out_bs + (size_t)n * 128 + col0;
    if (SPLIT) {
        union { unsigned short u[4]; uint2 q; } qh, ql;
        float f[4] = {r.x, r.y, r.z, r.w};
#pragma unroll
        for (int i = 0; i < 4; i++) {
            qh.u[i] = f2bf(f[i]);
            ql.u[i] = f2bf(f[i] - bf2f(qh.u[i]));
        }
        *(uint2*)((unsigned short*)o1 + oi) = qh.q;
        *(uint2*)((unsigned short*)o2 + oi) = ql.q;
    } else {
        *(float4*)((float*)o1 + oi) = r;
    }
}

// ---------------- aggregation (bf16 src -> fp32 out + bias): agg2 ----------------
// Same geometry as k_aggs; strips are 64 B/row (1.28 MB per pass-batch).

__global__ void k_aggb(const unsigned short* __restrict__ feat, long feat_bs,
                       const int* __restrict__ offs, long off_bs,
                       const int* __restrict__ elist, long el_bs,
                       const float* __restrict__ bias,
                       float* __restrict__ outp, long out_bs, int N) {
    __shared__ int ldspad[16384];    // 64 KB occupancy cap
    if (N < 0) {
        volatile int* vp = ldspad;
        vp[threadIdx.x] = (int)off_bs;
        if (vp[0] == 42) return;
    }
    int b = blockIdx.z, pass = blockIdx.y;
    int g = threadIdx.x >> 3;
    int lane = threadIdx.x & 7;
    int n = blockIdx.x * 32 + g;
    if (n >= N) return;
    int col0 = pass * 32 + lane * 4;
    const unsigned short* fp = feat + (size_t)b * feat_bs + col0;
    const int* off = offs + (size_t)b * off_bs;
    const int* el = elist + (size_t)b * el_bs;
    int lo = off[n], hi = off[n + 1];
    float4 a0 = make_float4(0.f, 0.f, 0.f, 0.f);
    float4 a1 = make_float4(0.f, 0.f, 0.f, 0.f);
    float4 a2 = make_float4(0.f, 0.f, 0.f, 0.f);
    float4 a3 = make_float4(0.f, 0.f, 0.f, 0.f);
    auto acc = [&](float4& a, ushort4 v) {
        a.x += bf2f(v.x); a.y += bf2f(v.y); a.z += bf2f(v.z); a.w += bf2f(v.w);
    };
    int e = lo;
    for (; e < hi && (e & 3); e++)
        acc(a0, *(const ushort4*)&fp[(size_t)el[e] * 128]);
    for (; e + 4 <= hi; e += 4) {
        int4 idx = *(const int4*)&el[e];
        ushort4 v0 = *(const ushort4*)&fp[(size_t)idx.x * 128];
        ushort4 v1 = *(const ushort4*)&fp[(size_t)idx.y * 128];
        ushort4 v2 = *(const ushort4*)&fp[(size_t)idx.z * 128];
        ushort4 v3 = *(const ushort4*)&fp[(size_t)idx.w * 128];
        acc(a0, v0); acc(a1, v1); acc(a2, v2); acc(a3, v3);
    }
    for (; e < hi; e++)
        acc(a0, *(const ushort4*)&fp[(size_t)el[e] * 128]);
    float4 r;
    r.x = (a0.x + a1.x) + (a2.x + a3.x);
    r.y = (a0.y + a1.y) + (a2.y + a3.y);
    r.z = (a0.z + a1.z) + (a2.z + a3.z);
    r.w = (a0.w + a1.w) + (a2.w + a3.w);
    float4 bv = *(const float4*)&bias[col0];
    r.x += bv.x; r.y += bv.y; r.z += bv.z; r.w += bv.w;
    *(float4*)&outp[(size_t)b * out_bs + (size_t)n * 128 + col0] = r;
}

// ---------------- W prep: fp32 [K][N] -> transposed split bf16 [N][K] ----------------

__global__ void k_prep_w(const float* __restrict__ W1, const float* __restrict__ W2,
                         unsigned short* __restrict__ Wt1h, unsigned short* __restrict__ Wt1l,
                         unsigned short* __restrict__ Wt2h, unsigned short* __restrict__ Wt2l) {
    int i = blockIdx.x * 256 + threadIdx.x;
    if (i < 128 * 256) {
        {   // W1 [128][256] -> Wt1 [256][128]
            int k = i / 256, n = i % 256;
            float v = W1[i];
            unsigned short h = f2bf(v);
            Wt1h[n * 128 + k] = h;
            Wt1l[n * 128 + k] = f2bf(v - bf2f(h));
        }
        {   // W2 [256][128] -> Wt2 [128][256]
            int k = i / 128, n = i % 128;
            float v = W2[i];
            unsigned short h = f2bf(v);
            Wt2h[n * 256 + k] = h;
            Wt2l[n * 256 + k] = f2bf(v - bf2f(h));
        }
    }
}

// ---------------- split-bf16 MFMA GEMM, swapped operands, MF=2, col-split ----------------
// OUT_MODE: 0 = fp32, 1 = split bf16 (hi/lo), 2 = single bf16.

template <int KSTEPS, int NFRAG, int KCHUNKS, bool RELU, int OUT_MODE>
__launch_bounds__(256)
__global__ void k_lin(const unsigned short* __restrict__ Ah,
                      const unsigned short* __restrict__ Al, long A_bs,
                      const unsigned short* __restrict__ Wth,
                      const unsigned short* __restrict__ Wtl,
                      const float* __restrict__ bias,   // nullable
                      void* __restrict__ C1, void* __restrict__ C2, long C_bs,
                      int M, int ncTot) {
    constexpr int K = KSTEPS * 32 * KCHUNKS;
    int b = blockIdx.z;
    int woff = blockIdx.y * (NFRAG * 16);
    int w = threadIdx.x >> 6, lane = threadIdx.x & 63;
    int colg = lane & 15, kg = lane >> 4;
    int rbase = blockIdx.x * 128 + w * 32;
    int row0 = rbase + colg;
    int row1 = rbase + 16 + colg;
    bool ok0 = row0 < M, ok1 = row1 < M;
    int rc0 = ok0 ? row0 : M - 1;
    int rc1 = ok1 ? row1 : M - 1;
    const unsigned short* pah0 = Ah + (size_t)b * A_bs + (size_t)rc0 * K + kg * 8;
    const unsigned short* pal0 = Al + (size_t)b * A_bs + (size_t)rc0 * K + kg * 8;
    const unsigned short* pah1 = Ah + (size_t)b * A_bs + (size_t)rc1 * K + kg * 8;
    const unsigned short* pal1 = Al + (size_t)b * A_bs + (size_t)rc1 * K + kg * 8;

    bf16x8 fah[2][KSTEPS], fal[2][KSTEPS];
    bf16x8 whA[KSTEPS], wlA[KSTEPS], whB[KSTEPS], wlB[KSTEPS];
    constexpr int NACC = (KCHUNKS > 1) ? NFRAG : 2;
    f32x4 acc[NACC][2];
#pragma unroll
    for (int i = 0; i < NACC; i++) {
        acc[i][0] = (f32x4){0.f, 0.f, 0.f, 0.f};
        acc[i][1] = (f32x4){0.f, 0.f, 0.f, 0.f};
    }

    auto loadW = [&](bf16x8* wh, bf16x8* wl, int nf, int kc) {
        const unsigned short* ph = Wth + (size_t)(woff + nf * 16 + colg) * K + kc * (KSTEPS * 32) + kg * 8;
        const unsigned short* pl = Wtl + (size_t)(woff + nf * 16 + colg) * K + kc * (KSTEPS * 32) + kg * 8;
#pragma unroll
        for (int ks = 0; ks < KSTEPS; ks++) {
            wh[ks] = *(const bf16x8*)(ph + ks * 32);
            wl[ks] = *(const bf16x8*)(pl + ks * 32);
        }
    };
    auto mm = [&](bf16x8* wh, bf16x8* wl, f32x4& c0, f32x4& c1) {
#pragma unroll
        for (int ks = 0; ks < KSTEPS; ks++) {
            c0 = __builtin_amdgcn_mfma_f32_16x16x32_bf16(wh[ks], fah[0][ks], c0, 0, 0, 0);
            c1 = __builtin_amdgcn_mfma_f32_16x16x32_bf16(wh[ks], fah[1][ks], c1, 0, 0, 0);
            c0 = __builtin_amdgcn_mfma_f32_16x16x32_bf16(wl[ks], fah[0][ks], c0, 0, 0, 0);
            c1 = __builtin_amdgcn_mfma_f32_16x16x32_bf16(wl[ks], fah[1][ks], c1, 0, 0, 0);
            c0 = __builtin_amdgcn_mfma_f32_16x16x32_bf16(wh[ks], fal[0][ks], c0, 0, 0, 0);
            c1 = __builtin_amdgcn_mfma_f32_16x16x32_bf16(wh[ks], fal[1][ks], c1, 0, 0, 0);
        }
    };
    auto epi = [&](f32x4 a, int nf, int mf) {
        bool ok = mf ? ok1 : ok0;
        if (!ok) return;
        int row = mf ? row1 : row0;
        int c0 = woff + nf * 16 + kg * 4;
        float v[4] = {a[0], a[1], a[2], a[3]};
        if (bias) {
            float4 bv = *(const float4*)&bias[c0];
            v[0] += bv.x; v[1] += bv.y; v[2] += bv.z; v[3] += bv.w;
        }
        if (RELU) {
#pragma unroll
            for (int j = 0; j < 4; j++) v[j] = fmaxf(v[j], 0.f);
        }
        size_t ci = (size_t)b * C_bs + (size_t)row * ncTot + c0;
        if constexpr (OUT_MODE == 1) {
            union { unsigned short u[4]; uint2 q; } qh, ql;
#pragma unroll
            for (int j = 0; j < 4; j++) {
                qh.u[j] = f2bf(v[j]);
                ql.u[j] = f2bf(v[j] - bf2f(qh.u[j]));
            }
            *(uint2*)((unsigned short*)C1 + ci) = qh.q;
            *(uint2*)((unsigned short*)C2 + ci) = ql.q;
        } else if constexpr (OUT_MODE == 2) {
            union { unsigned short u[4]; uint2 q; } qh;
#pragma unroll
            for (int j = 0; j < 4; j++) qh.u[j] = f2bf(v[j]);
            *(uint2*)((unsigned short*)C1 + ci) = qh.q;
        } else {
            *(float4*)((float*)C1 + ci) = make_float4(v[0], v[1], v[2], v[3]);
        }
    };

#pragma unroll
    for (int kc = 0; kc < KCHUNKS; kc++) {
#pragma unroll
        for (int ks = 0; ks < KSTEPS; ks++) {
            fah[0][ks] = *(const bf16x8*)(pah0 + kc * (KSTEPS * 32) + ks * 32);
            fal[0][ks] = *(const bf16x8*)(pal0 + kc * (KSTEPS * 32) + ks * 32);
            fah[1][ks] = *(const bf16x8*)(pah1 + kc * (KSTEPS * 32) + ks * 32);
            fal[1][ks] = *(const bf16x8*)(pal1 + kc * (KSTEPS * 32) + ks * 32);
        }
        loadW(whA, wlA, 0, kc);
#pragma unroll
        for (int nf = 0; nf < NFRAG; nf += 2) {
            loadW(whB, wlB, nf + 1, kc);
            if constexpr (KCHUNKS > 1) {
                mm(whA, wlA, acc[nf][0], acc[nf][1]);
            } else {
                f32x4 a0 = (f32x4){0.f, 0.f, 0.f, 0.f};
                f32x4 a1 = (f32x4){0.f, 0.f, 0.f, 0.f};
                mm(whA, wlA, a0, a1);
                epi(a0, nf, 0);
                epi(a1, nf, 1);
            }
            if (nf + 2 < NFRAG) loadW(whA, wlA, nf + 2, kc);
            if constexpr (KCHUNKS > 1) {
                mm(whB, wlB, acc[nf + 1][0], acc[nf + 1][1]);
            } else {
                f32x4 a0 = (f32x4){0.f, 0.f, 0.f, 0.f};
                f32x4 a1 = (f32x4){0.f, 0.f, 0.f, 0.f};
                mm(whB, wlB, a0, a1);
                epi(a0, nf + 1, 0);
                epi(a1, nf + 1, 1);
            }
        }
    }
    if constexpr (KCHUNKS > 1) {
#pragma unroll
        for (int nf = 0; nf < NFRAG; nf++) {
            epi(acc[nf][0], nf, 0);
            epi(acc[nf][1], nf, 1);
        }
    }
}

// ---------------- host ----------------

extern "C" void kernel_launch(void* const* d_in, const int* in_sizes, int n_in,
                              void* d_out, int out_size, void* d_ws, size_t ws_size,
                              hipStream_t stream) {
    const float* features = (const float*)d_in[0];  // [B,N,128]
    const int* src = (const int*)d_in[1];           // [B,E]
    const int* dst = (const int*)d_in[2];           // [B,E]
    const float* W1 = (const float*)d_in[3];        // [128,256]
    const float* b1 = (const float*)d_in[4];        // [256]
    const float* W2 = (const float*)d_in[5];        // [256,128]
    const float* b2 = (const float*)d_in[6];        // [128]
    float* out = (float*)d_out;                     // [B,N,128]

    const int B = 4;
    const int N = NN;
    const int E = in_sizes[1] / B;

    auto need = [&](int nb) -> size_t {
        size_t bf = ((size_t)nb * N * (128 * 2 + 256 * 2 + 128)) * sizeof(unsigned short);
        size_t wt = 4 * 32768 * sizeof(unsigned short);
        size_t ints = (size_t)nb * ((size_t)(N + 1) + N + E) * sizeof(int);
        return bf + wt + ints;
    };
    int nb = (ws_size >= need(4)) ? 4 : 1;
    int npass = B / nb;

    char* p = (char*)d_ws;
    unsigned short* A1h = (unsigned short*)p; p += (size_t)nb * N * 128 * sizeof(unsigned short);
    unsigned short* A1l = (unsigned short*)p; p += (size_t)nb * N * 128 * sizeof(unsigned short);
    unsigned short* Hh  = (unsigned short*)p; p += (size_t)nb * N * 256 * sizeof(unsigned short);
    unsigned short* Hl  = (unsigned short*)p; p += (size_t)nb * N * 256 * sizeof(unsigned short);
    unsigned short* H2b = (unsigned short*)p; p += (size_t)nb * N * 128 * sizeof(unsigned short);
    unsigned short* Wt1h = (unsigned short*)p; p += 32768 * sizeof(unsigned short);
    unsigned short* Wt1l = (unsigned short*)p; p += 32768 * sizeof(unsigned short);
    unsigned short* Wt2h = (unsigned short*)p; p += 32768 * sizeof(unsigned short);
    unsigned short* Wt2l = (unsigned short*)p; p += 32768 * sizeof(unsigned short);
    int* offs = (int*)p;  p += (size_t)nb * (N + 1) * sizeof(int);
    int* curs = (int*)p;  p += (size_t)nb * N * sizeof(int);
    int* elist = (int*)p;

    k_prep_w<<<128, 256, 0, stream>>>(W1, W2, Wt1h, Wt1l, Wt2h, Wt2l);

    for (int pass = 0; pass < npass; pass++) {
        int b0 = pass * nb;
        const float* feat_p = features + (size_t)b0 * N * 128;
        const int* src_p = src + (size_t)b0 * E;
        const int* dst_p = dst + (size_t)b0 * E;
        float* out_p = out + (size_t)b0 * N * 128;

        hipMemsetAsync(curs, 0, (size_t)nb * N * sizeof(int), stream);

        dim3 gE((E + 255) / 256, 1, nb);
        k_count<<<gE, 256, 0, stream>>>(dst_p, E, curs, N, E);
        k_scan<<<dim3(1, 1, nb), 1024, 0, stream>>>(curs, N, offs, N + 1, curs, N, N);
        k_fill<<<gE, 256, 0, stream>>>(src_p, E, dst_p, E, curs, N, elist, E, E);

        dim3 gAgg((N + 31) / 32, 4, nb);   // y = column-strip pass
        // conv1 aggregation -> split bf16: (A1h, A1l) = segsum(feat[src] -> dst)
        k_aggs<true><<<gAgg, 256, 0, stream>>>(feat_p, (long)N * 128, offs, N + 1,
                                               elist, E, nullptr, A1h, A1l, (long)N * 128, N);
        // conv1 linear + bias + relu -> split bf16: (Hh, Hl); y splits 256 cols in 2
        k_lin<4, 8, 1, true, 1><<<dim3((N + 127) / 128, 2, nb), 256, 0, stream>>>(
            A1h, A1l, (long)N * 128, Wt1h, Wt1l, b1, Hh, Hl, (long)N * 256, N, 256);
        // conv2 linear (agg commutes): H2b = bf16(H @ W2); y splits 128 cols in 2
        k_lin<4, 4, 2, false, 2><<<dim3((N + 127) / 128, 2, nb), 256, 0, stream>>>(
            Hh, Hl, (long)N * 256, Wt2h, Wt2l, nullptr, H2b, nullptr, (long)N * 128, N, 128);
        // conv2 aggregation + bias: out = segsum(H2b[src] -> dst) + b2
        k_aggb<<<gAgg, 256, 0, stream>>>(H2b, (long)N * 128, offs, N + 1,
                                         elist, E, b2, out_p, (long)N * 128, N);
    }
}

// Round 8
// 411.744 us; speedup vs baseline: 1.4685x; 1.4685x over previous
//
#include <hip/hip_runtime.h>

#define NN 20000   // nodes per graph

typedef __attribute__((ext_vector_type(8))) __bf16 bf16x8;
typedef __attribute__((ext_vector_type(8))) unsigned short ushort8;
typedef __attribute__((ext_vector_type(4))) float f32x4;

__device__ __forceinline__ unsigned short f2bf(float f) {
    unsigned u = __builtin_bit_cast(unsigned, f);
    u += 0x7fff + ((u >> 16) & 1);   // round-to-nearest-even
    return (unsigned short)(u >> 16);
}
__device__ __forceinline__ float bf2f(unsigned short h) {
    unsigned u = ((unsigned)h) << 16;
    return __builtin_bit_cast(float, u);
}

// ---------------- fp32 -> bf16 streaming convert ----------------

__global__ void k_tobf(const float* __restrict__ in, unsigned short* __restrict__ outp,
                       long n8) {
    long i = (long)blockIdx.x * 256 + threadIdx.x;
    if (i >= n8) return;
    const float4* s = (const float4*)(in + i * 8);
    float4 v0 = s[0], v1 = s[1];
    ushort8 r;
    r[0] = f2bf(v0.x); r[1] = f2bf(v0.y); r[2] = f2bf(v0.z); r[3] = f2bf(v0.w);
    r[4] = f2bf(v1.x); r[5] = f2bf(v1.y); r[6] = f2bf(v1.z); r[7] = f2bf(v1.w);
    *(ushort8*)(outp + i * 8) = r;
}

// ---------------- CSR build ----------------

__global__ void k_count(const int* __restrict__ dst, long dst_bs,
                        int* __restrict__ counts, long cnt_bs, int E) {
    int b = blockIdx.z;
    const int* d = dst + (size_t)b * dst_bs;
    int* c = counts + (size_t)b * cnt_bs;
    for (int e = blockIdx.x * blockDim.x + threadIdx.x; e < E; e += gridDim.x * blockDim.x)
        atomicAdd(&c[d[e]], 1);
}

// one 1024-thread block per batch: exclusive scan of counts -> offs, cursor
__global__ void k_scan(const int* __restrict__ counts, long cnt_bs,
                       int* __restrict__ offs, long off_bs,
                       int* __restrict__ cursor, long cur_bs, int n) {
    int b = blockIdx.z;
    const int* cnt = counts + (size_t)b * cnt_bs;
    int* off = offs + (size_t)b * off_bs;
    int* cur = cursor + (size_t)b * cur_bs;
    __shared__ int sums[1024];
    int t = threadIdx.x;
    int chunk = (n + 1023) / 1024;
    int lo = t * chunk;
    int hi = min(lo + chunk, n);
    int s = 0;
    for (int i = lo; i < hi; i++) s += cnt[i];
    sums[t] = s;
    __syncthreads();
    for (int d2 = 1; d2 < 1024; d2 <<= 1) {
        int x = (t >= d2) ? sums[t - d2] : 0;
        __syncthreads();
        sums[t] += x;
        __syncthreads();
    }
    if (t == 1023) off[n] = sums[1023];
    int run = sums[t] - s;
    for (int i = lo; i < hi; i++) {
        int c = cnt[i];
        off[i] = run;
        cur[i] = run;
        run += c;
    }
}

__global__ void k_fill(const int* __restrict__ src, long src_bs,
                       const int* __restrict__ dst, long dst_bs,
                       int* __restrict__ cursor, long cur_bs,
                       int* __restrict__ elist, long el_bs, int E) {
    int b = blockIdx.z;
    const int* s = src + (size_t)b * src_bs;
    const int* d = dst + (size_t)b * dst_bs;
    int* cur = cursor + (size_t)b * cur_bs;
    int* el = elist + (size_t)b * el_bs;
    for (int e = blockIdx.x * blockDim.x + threadIdx.x; e < E; e += gridDim.x * blockDim.x) {
        int p = atomicAdd(&cur[d[e]], 1);
        el[p] = s[e];
    }
}

// ---------------- bf16 aggregation: 64-col strips, 8-lane groups, 4-edge unroll ----------
// grid = (N/32, 2 passes, nb). Per-pass strip = N*128 B = 2.56 MB (L2-scale).
// Each lane handles 8 bf16 cols (16 B); one wave instr gathers 8 rows x 128 B.
// SPLIT: write hi/lo bf16 pair; else fp32 + bias.

template <bool SPLIT>
__global__ void k_agg(const unsigned short* __restrict__ feat, long feat_bs,
                      const int* __restrict__ offs, long off_bs,
                      const int* __restrict__ elist, long el_bs,
                      const float* __restrict__ bias,   // nullable
                      void* __restrict__ o1, void* __restrict__ o2,
                      long out_bs, int N) {
    int b = blockIdx.z, pass = blockIdx.y;
    int g = threadIdx.x >> 3;        // 32 groups per 256-block
    int lane = threadIdx.x & 7;      // 8 lanes * 8 bf16 = 64 cols
    int n = blockIdx.x * 32 + g;
    if (n >= N) return;
    int col0 = pass * 64 + lane * 8;
    const unsigned short* fp = feat + (size_t)b * feat_bs + col0;
    const int* off = offs + (size_t)b * off_bs;
    const int* el = elist + (size_t)b * el_bs;
    int lo = off[n], hi = off[n + 1];
    float a0[8] = {}, a1[8] = {}, a2[8] = {}, a3[8] = {};
    auto acc = [&](float* a, ushort8 v) {
#pragma unroll
        for (int i = 0; i < 8; i++) a[i] += bf2f(v[i]);
    };
    int e = lo;
    for (; e < hi && (e & 3); e++)
        acc(a0, *(const ushort8*)&fp[(size_t)el[e] * 128]);
    for (; e + 4 <= hi; e += 4) {
        int4 idx = *(const int4*)&el[e];
        ushort8 v0 = *(const ushort8*)&fp[(size_t)idx.x * 128];
        ushort8 v1 = *(const ushort8*)&fp[(size_t)idx.y * 128];
        ushort8 v2 = *(const ushort8*)&fp[(size_t)idx.z * 128];
        ushort8 v3 = *(const ushort8*)&fp[(size_t)idx.w * 128];
        acc(a0, v0); acc(a1, v1); acc(a2, v2); acc(a3, v3);
    }
    for (; e < hi; e++)
        acc(a0, *(const ushort8*)&fp[(size_t)el[e] * 128]);
    float r[8];
#pragma unroll
    for (int i = 0; i < 8; i++) r[i] = (a0[i] + a1[i]) + (a2[i] + a3[i]);
    size_t oi = (size_t)b * out_bs + (size_t)n * 128 + col0;
    if (SPLIT) {
        ushort8 qh, ql;
#pragma unroll
        for (int i = 0; i < 8; i++) {
            qh[i] = f2bf(r[i]);
            ql[i] = f2bf(r[i] - bf2f(qh[i]));
        }
        *(ushort8*)((unsigned short*)o1 + oi) = qh;
        *(ushort8*)((unsigned short*)o2 + oi) = ql;
    } else {
        float* op = (float*)o1 + oi;
        const float* bp = bias + col0;
#pragma unroll
        for (int i = 0; i < 8; i++) r[i] += bp[i];
        *(float4*)(op) = make_float4(r[0], r[1], r[2], r[3]);
        *(float4*)(op + 4) = make_float4(r[4], r[5], r[6], r[7]);
    }
}

// ---------------- W prep: fp32 [K][N] -> transposed split bf16 [N][K] ----------------

__global__ void k_prep_w(const float* __restrict__ W1, const float* __restrict__ W2,
                         unsigned short* __restrict__ Wt1h, unsigned short* __restrict__ Wt1l,
                         unsigned short* __restrict__ Wt2h, unsigned short* __restrict__ Wt2l) {
    int i = blockIdx.x * 256 + threadIdx.x;
    if (i < 128 * 256) {
        {   // W1 [128][256] -> Wt1 [256][128]
            int k = i / 256, n = i % 256;
            float v = W1[i];
            unsigned short h = f2bf(v);
            Wt1h[n * 128 + k] = h;
            Wt1l[n * 128 + k] = f2bf(v - bf2f(h));
        }
        {   // W2 [256][128] -> Wt2 [128][256]
            int k = i / 128, n = i % 128;
            float v = W2[i];
            unsigned short h = f2bf(v);
            Wt2h[n * 256 + k] = h;
            Wt2l[n * 256 + k] = f2bf(v - bf2f(h));
        }
    }
}

// ---------------- split-bf16 MFMA GEMM, swapped operands, MF=2, col-split ----------------
// OUT_MODE: 0 = fp32, 1 = split bf16 (hi/lo), 2 = single bf16.

template <int KSTEPS, int NFRAG, int KCHUNKS, bool RELU, int OUT_MODE>
__launch_bounds__(256)
__global__ void k_lin(const unsigned short* __restrict__ Ah,
                      const unsigned short* __restrict__ Al, long A_bs,
                      const unsigned short* __restrict__ Wth,
                      const unsigned short* __restrict__ Wtl,
                      const float* __restrict__ bias,   // nullable
                      void* __restrict__ C1, void* __restrict__ C2, long C_bs,
                      int M, int ncTot) {
    constexpr int K = KSTEPS * 32 * KCHUNKS;
    int b = blockIdx.z;
    int woff = blockIdx.y * (NFRAG * 16);
    int w = threadIdx.x >> 6, lane = threadIdx.x & 63;
    int colg = lane & 15, kg = lane >> 4;
    int rbase = blockIdx.x * 128 + w * 32;
    int row0 = rbase + colg;
    int row1 = rbase + 16 + colg;
    bool ok0 = row0 < M, ok1 = row1 < M;
    int rc0 = ok0 ? row0 : M - 1;
    int rc1 = ok1 ? row1 : M - 1;
    const unsigned short* pah0 = Ah + (size_t)b * A_bs + (size_t)rc0 * K + kg * 8;
    const unsigned short* pal0 = Al + (size_t)b * A_bs + (size_t)rc0 * K + kg * 8;
    const unsigned short* pah1 = Ah + (size_t)b * A_bs + (size_t)rc1 * K + kg * 8;
    const unsigned short* pal1 = Al + (size_t)b * A_bs + (size_t)rc1 * K + kg * 8;

    bf16x8 fah[2][KSTEPS], fal[2][KSTEPS];
    bf16x8 whA[KSTEPS], wlA[KSTEPS], whB[KSTEPS], wlB[KSTEPS];
    constexpr int NACC = (KCHUNKS > 1) ? NFRAG : 2;
    f32x4 acc[NACC][2];
#pragma unroll
    for (int i = 0; i < NACC; i++) {
        acc[i][0] = (f32x4){0.f, 0.f, 0.f, 0.f};
        acc[i][1] = (f32x4){0.f, 0.f, 0.f, 0.f};
    }

    auto loadW = [&](bf16x8* wh, bf16x8* wl, int nf, int kc) {
        const unsigned short* ph = Wth + (size_t)(woff + nf * 16 + colg) * K + kc * (KSTEPS * 32) + kg * 8;
        const unsigned short* pl = Wtl + (size_t)(woff + nf * 16 + colg) * K + kc * (KSTEPS * 32) + kg * 8;
#pragma unroll
        for (int ks = 0; ks < KSTEPS; ks++) {
            wh[ks] = *(const bf16x8*)(ph + ks * 32);
            wl[ks] = *(const bf16x8*)(pl + ks * 32);
        }
    };
    auto mm = [&](bf16x8* wh, bf16x8* wl, f32x4& c0, f32x4& c1) {
#pragma unroll
        for (int ks = 0; ks < KSTEPS; ks++) {
            c0 = __builtin_amdgcn_mfma_f32_16x16x32_bf16(wh[ks], fah[0][ks], c0, 0, 0, 0);
            c1 = __builtin_amdgcn_mfma_f32_16x16x32_bf16(wh[ks], fah[1][ks], c1, 0, 0, 0);
            c0 = __builtin_amdgcn_mfma_f32_16x16x32_bf16(wl[ks], fah[0][ks], c0, 0, 0, 0);
            c1 = __builtin_amdgcn_mfma_f32_16x16x32_bf16(wl[ks], fah[1][ks], c1, 0, 0, 0);
            c0 = __builtin_amdgcn_mfma_f32_16x16x32_bf16(wh[ks], fal[0][ks], c0, 0, 0, 0);
            c1 = __builtin_amdgcn_mfma_f32_16x16x32_bf16(wh[ks], fal[1][ks], c1, 0, 0, 0);
        }
    };
    auto epi = [&](f32x4 a, int nf, int mf) {
        bool ok = mf ? ok1 : ok0;
        if (!ok) return;
        int row = mf ? row1 : row0;
        int c0 = woff + nf * 16 + kg * 4;
        float v[4] = {a[0], a[1], a[2], a[3]};
        if (bias) {
            float4 bv = *(const float4*)&bias[c0];
            v[0] += bv.x; v[1] += bv.y; v[2] += bv.z; v[3] += bv.w;
        }
        if (RELU) {
#pragma unroll
            for (int j = 0; j < 4; j++) v[j] = fmaxf(v[j], 0.f);
        }
        size_t ci = (size_t)b * C_bs + (size_t)row * ncTot + c0;
        if constexpr (OUT_MODE == 1) {
            union { unsigned short u[4]; uint2 q; } qh, ql;
#pragma unroll
            for (int j = 0; j < 4; j++) {
                qh.u[j] = f2bf(v[j]);
                ql.u[j] = f2bf(v[j] - bf2f(qh.u[j]));
            }
            *(uint2*)((unsigned short*)C1 + ci) = qh.q;
            *(uint2*)((unsigned short*)C2 + ci) = ql.q;
        } else if constexpr (OUT_MODE == 2) {
            union { unsigned short u[4]; uint2 q; } qh;
#pragma unroll
            for (int j = 0; j < 4; j++) qh.u[j] = f2bf(v[j]);
            *(uint2*)((unsigned short*)C1 + ci) = qh.q;
        } else {
            *(float4*)((float*)C1 + ci) = make_float4(v[0], v[1], v[2], v[3]);
        }
    };

#pragma unroll
    for (int kc = 0; kc < KCHUNKS; kc++) {
#pragma unroll
        for (int ks = 0; ks < KSTEPS; ks++) {
            fah[0][ks] = *(const bf16x8*)(pah0 + kc * (KSTEPS * 32) + ks * 32);
            fal[0][ks] = *(const bf16x8*)(pal0 + kc * (KSTEPS * 32) + ks * 32);
            fah[1][ks] = *(const bf16x8*)(pah1 + kc * (KSTEPS * 32) + ks * 32);
            fal[1][ks] = *(const bf16x8*)(pal1 + kc * (KSTEPS * 32) + ks * 32);
        }
        loadW(whA, wlA, 0, kc);
#pragma unroll
        for (int nf = 0; nf < NFRAG; nf += 2) {
            loadW(whB, wlB, nf + 1, kc);
            if constexpr (KCHUNKS > 1) {
                mm(whA, wlA, acc[nf][0], acc[nf][1]);
            } else {
                f32x4 a0 = (f32x4){0.f, 0.f, 0.f, 0.f};
                f32x4 a1 = (f32x4){0.f, 0.f, 0.f, 0.f};
                mm(whA, wlA, a0, a1);
                epi(a0, nf, 0);
                epi(a1, nf, 1);
            }
            if (nf + 2 < NFRAG) loadW(whA, wlA, nf + 2, kc);
            if constexpr (KCHUNKS > 1) {
                mm(whB, wlB, acc[nf + 1][0], acc[nf + 1][1]);
            } else {
                f32x4 a0 = (f32x4){0.f, 0.f, 0.f, 0.f};
                f32x4 a1 = (f32x4){0.f, 0.f, 0.f, 0.f};
                mm(whB, wlB, a0, a1);
                epi(a0, nf + 1, 0);
                epi(a1, nf + 1, 1);
            }
        }
    }
    if constexpr (KCHUNKS > 1) {
#pragma unroll
        for (int nf = 0; nf < NFRAG; nf++) {
            epi(acc[nf][0], nf, 0);
            epi(acc[nf][1], nf, 1);
        }
    }
}

// ---------------- host ----------------

extern "C" void kernel_launch(void* const* d_in, const int* in_sizes, int n_in,
                              void* d_out, int out_size, void* d_ws, size_t ws_size,
                              hipStream_t stream) {
    const float* features = (const float*)d_in[0];  // [B,N,128]
    const int* src = (const int*)d_in[1];           // [B,E]
    const int* dst = (const int*)d_in[2];           // [B,E]
    const float* W1 = (const float*)d_in[3];        // [128,256]
    const float* b1 = (const float*)d_in[4];        // [256]
    const float* W2 = (const float*)d_in[5];        // [256,128]
    const float* b2 = (const float*)d_in[6];        // [128]
    float* out = (float*)d_out;                     // [B,N,128]

    const int B = 4;
    const int N = NN;
    const int E = in_sizes[1] / B;

    auto need = [&](int nb) -> size_t {
        size_t bf = ((size_t)nb * N * (128 + 128 * 2 + 256 * 2 + 128)) * sizeof(unsigned short);
        size_t wt = 4 * 32768 * sizeof(unsigned short);
        size_t ints = (size_t)nb * ((size_t)(N + 1) + N + E) * sizeof(int);
        return bf + wt + ints;
    };
    int nb = (ws_size >= need(4)) ? 4 : 1;
    int npass = B / nb;

    char* p = (char*)d_ws;
    unsigned short* fb  = (unsigned short*)p; p += (size_t)nb * N * 128 * sizeof(unsigned short);
    unsigned short* A1h = (unsigned short*)p; p += (size_t)nb * N * 128 * sizeof(unsigned short);
    unsigned short* A1l = (unsigned short*)p; p += (size_t)nb * N * 128 * sizeof(unsigned short);
    unsigned short* Hh  = (unsigned short*)p; p += (size_t)nb * N * 256 * sizeof(unsigned short);
    unsigned short* Hl  = (unsigned short*)p; p += (size_t)nb * N * 256 * sizeof(unsigned short);
    unsigned short* H2b = (unsigned short*)p; p += (size_t)nb * N * 128 * sizeof(unsigned short);
    unsigned short* Wt1h = (unsigned short*)p; p += 32768 * sizeof(unsigned short);
    unsigned short* Wt1l = (unsigned short*)p; p += 32768 * sizeof(unsigned short);
    unsigned short* Wt2h = (unsigned short*)p; p += 32768 * sizeof(unsigned short);
    unsigned short* Wt2l = (unsigned short*)p; p += 32768 * sizeof(unsigned short);
    int* offs = (int*)p;  p += (size_t)nb * (N + 1) * sizeof(int);
    int* curs = (int*)p;  p += (size_t)nb * N * sizeof(int);
    int* elist = (int*)p;

    k_prep_w<<<128, 256, 0, stream>>>(W1, W2, Wt1h, Wt1l, Wt2h, Wt2l);

    for (int pass = 0; pass < npass; pass++) {
        int b0 = pass * nb;
        const float* feat_p = features + (size_t)b0 * N * 128;
        const int* src_p = src + (size_t)b0 * E;
        const int* dst_p = dst + (size_t)b0 * E;
        float* out_p = out + (size_t)b0 * N * 128;

        hipMemsetAsync(curs, 0, (size_t)nb * N * sizeof(int), stream);

        // features -> bf16 (streaming)
        long n8 = (long)nb * N * 128 / 8;
        k_tobf<<<(int)((n8 + 255) / 256), 256, 0, stream>>>(feat_p, fb, n8);

        dim3 gE((E + 255) / 256, 1, nb);
        k_count<<<gE, 256, 0, stream>>>(dst_p, E, curs, N, E);
        k_scan<<<dim3(1, 1, nb), 1024, 0, stream>>>(curs, N, offs, N + 1, curs, N, N);
        k_fill<<<gE, 256, 0, stream>>>(src_p, E, dst_p, E, curs, N, elist, E, E);

        dim3 gAgg((N + 31) / 32, 2, nb);   // y = 64-col strip pass
        // conv1 aggregation (bf16 gather) -> split bf16 (A1h, A1l)
        k_agg<true><<<gAgg, 256, 0, stream>>>(fb, (long)N * 128, offs, N + 1,
                                              elist, E, nullptr, A1h, A1l, (long)N * 128, N);
        // conv1 linear + bias + relu -> split bf16 (Hh, Hl); y splits 256 cols in 2
        k_lin<4, 8, 1, true, 1><<<dim3((N + 127) / 128, 2, nb), 256, 0, stream>>>(
            A1h, A1l, (long)N * 128, Wt1h, Wt1l, b1, Hh, Hl, (long)N * 256, N, 256);
        // conv2 linear (agg commutes): H2b = bf16(H @ W2); y splits 128 cols in 2
        k_lin<4, 4, 2, false, 2><<<dim3((N + 127) / 128, 2, nb), 256, 0, stream>>>(
            Hh, Hl, (long)N * 256, Wt2h, Wt2l, nullptr, H2b, nullptr, (long)N * 128, N, 128);
        // conv2 aggregation (bf16 gather) + bias: out = segsum(H2b[src] -> dst) + b2
        k_agg<false><<<gAgg, 256, 0, stream>>>(H2b, (long)N * 128, offs, N + 1,
                                               elist, E, b2, out_p, nullptr, (long)N * 128, N);
    }
}

// Round 9
// 383.306 us; speedup vs baseline: 1.5774x; 1.0742x over previous
//
#include <hip/hip_runtime.h>

#define NN 20000   // nodes per graph

typedef __attribute__((ext_vector_type(8))) __bf16 bf16x8;
typedef __attribute__((ext_vector_type(8))) unsigned short ushort8;
typedef __attribute__((ext_vector_type(4))) float f32x4;

__device__ __forceinline__ unsigned short f2bf(float f) {
    unsigned u = __builtin_bit_cast(unsigned, f);
    u += 0x7fff + ((u >> 16) & 1);   // round-to-nearest-even
    return (unsigned short)(u >> 16);
}
__device__ __forceinline__ float bf2f(unsigned short h) {
    unsigned u = ((unsigned)h) << 16;
    return __builtin_bit_cast(float, u);
}

// ---------------- fp32 -> bf16 streaming convert ----------------

__global__ void k_tobf(const float* __restrict__ in, unsigned short* __restrict__ outp,
                       long n8) {
    long i = (long)blockIdx.x * 256 + threadIdx.x;
    if (i >= n8) return;
    const float4* s = (const float4*)(in + i * 8);
    float4 v0 = s[0], v1 = s[1];
    ushort8 r;
    r[0] = f2bf(v0.x); r[1] = f2bf(v0.y); r[2] = f2bf(v0.z); r[3] = f2bf(v0.w);
    r[4] = f2bf(v1.x); r[5] = f2bf(v1.y); r[6] = f2bf(v1.z); r[7] = f2bf(v1.w);
    *(ushort8*)(outp + i * 8) = r;
}

// ---------------- CSR build (XCD-affine: batch = (gid&7)%nb) ----------------

__global__ void k_count(const int* __restrict__ dst, long dst_bs,
                        int* __restrict__ counts, long cnt_bs, int E, int nb, int jpb) {
    int gid = blockIdx.x;
    int xcd = gid & 7;
    int b = xcd % nb;
    int xg = 8 / nb;
    int jj = (gid >> 3) * xg + (xcd / nb);
    if (jj >= jpb) return;
    int e = jj * 256 + threadIdx.x;
    if (e < E)
        atomicAdd(&counts[(size_t)b * cnt_bs + dst[(size_t)b * dst_bs + e]], 1);
}

// one 1024-thread block per batch: exclusive scan of counts -> offs, cursor
__global__ void k_scan(const int* __restrict__ counts, long cnt_bs,
                       int* __restrict__ offs, long off_bs,
                       int* __restrict__ cursor, long cur_bs, int n) {
    int b = blockIdx.z;
    const int* cnt = counts + (size_t)b * cnt_bs;
    int* off = offs + (size_t)b * off_bs;
    int* cur = cursor + (size_t)b * cur_bs;
    __shared__ int sums[1024];
    int t = threadIdx.x;
    int chunk = (n + 1023) / 1024;
    int lo = t * chunk;
    int hi = min(lo + chunk, n);
    int s = 0;
    for (int i = lo; i < hi; i++) s += cnt[i];
    sums[t] = s;
    __syncthreads();
    for (int d2 = 1; d2 < 1024; d2 <<= 1) {
        int x = (t >= d2) ? sums[t - d2] : 0;
        __syncthreads();
        sums[t] += x;
        __syncthreads();
    }
    if (t == 1023) off[n] = sums[1023];
    int run = sums[t] - s;
    for (int i = lo; i < hi; i++) {
        int c = cnt[i];
        off[i] = run;
        cur[i] = run;
        run += c;
    }
}

__global__ void k_fill(const int* __restrict__ src, long src_bs,
                       const int* __restrict__ dst, long dst_bs,
                       int* __restrict__ cursor, long cur_bs,
                       unsigned short* __restrict__ elist, long el_bs,
                       int E, int nb, int jpb) {
    int gid = blockIdx.x;
    int xcd = gid & 7;
    int b = xcd % nb;
    int xg = 8 / nb;
    int jj = (gid >> 3) * xg + (xcd / nb);
    if (jj >= jpb) return;
    int e = jj * 256 + threadIdx.x;
    if (e < E) {
        int d = dst[(size_t)b * dst_bs + e];
        int s = src[(size_t)b * src_bs + e];
        int p = atomicAdd(&cursor[(size_t)b * cur_bs + d], 1);
        elist[(size_t)b * el_bs + p] = (unsigned short)s;
    }
}

// ---------------- bf16 aggregation: 64-col strips, XCD-affine batches ----------------
// Per-batch work = NBX node-blocks x 2 passes; batch = (gid&7)%nb so each batch's
// 2.56 MB strip + elist live in 2 XCD L2s. 8 lanes * 8 bf16 = 64 cols/pass.

template <bool SPLIT>
__global__ void k_agg(const unsigned short* __restrict__ feat, long feat_bs,
                      const int* __restrict__ offs, long off_bs,
                      const unsigned short* __restrict__ elist, long el_bs,
                      const float* __restrict__ bias,   // nullable
                      void* __restrict__ o1, void* __restrict__ o2,
                      long out_bs, int N, int nb, int nbx) {
    int gid = blockIdx.x;
    int xcd = gid & 7;
    int b = xcd % nb;
    int xg = 8 / nb;
    int jj = (gid >> 3) * xg + (xcd / nb);
    if (jj >= 2 * nbx) return;
    int pass = (jj >= nbx) ? 1 : 0;
    int nbk = jj - pass * nbx;
    int g = threadIdx.x >> 3;        // 32 node-groups per block
    int lane = threadIdx.x & 7;
    int n = nbk * 32 + g;
    if (n >= N) return;
    int col0 = pass * 64 + lane * 8;
    const unsigned short* fp = feat + (size_t)b * feat_bs + col0;
    const int* off = offs + (size_t)b * off_bs;
    const unsigned short* el = elist + (size_t)b * el_bs;
    int lo = off[n], hi = off[n + 1];
    float a0[8] = {}, a1[8] = {}, a2[8] = {}, a3[8] = {};
    auto acc = [&](float* a, ushort8 v) {
#pragma unroll
        for (int i = 0; i < 8; i++) a[i] += bf2f(v[i]);
    };
    int e = lo;
    for (; e < hi && (e & 3); e++)
        acc(a0, *(const ushort8*)&fp[(size_t)el[e] * 128]);
    for (; e + 4 <= hi; e += 4) {
        ushort4 idx = *(const ushort4*)&el[e];
        ushort8 v0 = *(const ushort8*)&fp[(size_t)idx.x * 128];
        ushort8 v1 = *(const ushort8*)&fp[(size_t)idx.y * 128];
        ushort8 v2 = *(const ushort8*)&fp[(size_t)idx.z * 128];
        ushort8 v3 = *(const ushort8*)&fp[(size_t)idx.w * 128];
        acc(a0, v0); acc(a1, v1); acc(a2, v2); acc(a3, v3);
    }
    for (; e < hi; e++)
        acc(a0, *(const ushort8*)&fp[(size_t)el[e] * 128]);
    float r[8];
#pragma unroll
    for (int i = 0; i < 8; i++) r[i] = (a0[i] + a1[i]) + (a2[i] + a3[i]);
    size_t oi = (size_t)b * out_bs + (size_t)n * 128 + col0;
    if (SPLIT) {
        ushort8 qh, ql;
#pragma unroll
        for (int i = 0; i < 8; i++) {
            qh[i] = f2bf(r[i]);
            ql[i] = f2bf(r[i] - bf2f(qh[i]));
        }
        *(ushort8*)((unsigned short*)o1 + oi) = qh;
        *(ushort8*)((unsigned short*)o2 + oi) = ql;
    } else {
        float* op = (float*)o1 + oi;
        const float* bp = bias + col0;
#pragma unroll
        for (int i = 0; i < 8; i++) r[i] += bp[i];
        *(float4*)(op) = make_float4(r[0], r[1], r[2], r[3]);
        *(float4*)(op + 4) = make_float4(r[4], r[5], r[6], r[7]);
    }
}

// ---------------- W prep: fp32 [K][N] -> transposed split bf16 [N][K] ----------------

__global__ void k_prep_w(const float* __restrict__ W1, const float* __restrict__ W2,
                         unsigned short* __restrict__ Wt1h, unsigned short* __restrict__ Wt1l,
                         unsigned short* __restrict__ Wt2h, unsigned short* __restrict__ Wt2l) {
    int i = blockIdx.x * 256 + threadIdx.x;
    if (i < 128 * 256) {
        {   // W1 [128][256] -> Wt1 [256][128]
            int k = i / 256, n = i % 256;
            float v = W1[i];
            unsigned short h = f2bf(v);
            Wt1h[n * 128 + k] = h;
            Wt1l[n * 128 + k] = f2bf(v - bf2f(h));
        }
        {   // W2 [256][128] -> Wt2 [128][256]
            int k = i / 128, n = i % 128;
            float v = W2[i];
            unsigned short h = f2bf(v);
            Wt2h[n * 256 + k] = h;
            Wt2l[n * 256 + k] = f2bf(v - bf2f(h));
        }
    }
}

// ---------------- split-bf16 MFMA GEMM, swapped operands, LDS-staged epilogue ----------
// OUT_MODE: 1 = split bf16 (hi/lo), 2 = single bf16. Output tile staged in LDS
// (XOR-swizzled words) then written back as coalesced uint4 runs.

template <int KSTEPS, int NFRAG, int KCHUNKS, bool RELU, int OUT_MODE>
__launch_bounds__(256)
__global__ void k_lin(const unsigned short* __restrict__ Ah,
                      const unsigned short* __restrict__ Al, long A_bs,
                      const unsigned short* __restrict__ Wth,
                      const unsigned short* __restrict__ Wtl,
                      const float* __restrict__ bias,   // nullable
                      void* __restrict__ C1, void* __restrict__ C2, long C_bs,
                      int M, int ncTot) {
    constexpr int K = KSTEPS * 32 * KCHUNKS;
    constexpr int WPR = NFRAG * 8;           // LDS words per row of the col-slice
    __shared__ unsigned int ldsH[128 * WPR];
    __shared__ unsigned int ldsL[(OUT_MODE == 1) ? 128 * WPR : 4];
    int b = blockIdx.z;
    int woff = blockIdx.y * (NFRAG * 16);
    int w = threadIdx.x >> 6, lane = threadIdx.x & 63;
    int colg = lane & 15, kg = lane >> 4;
    int rbase = blockIdx.x * 128 + w * 32;
    int row0 = rbase + colg;
    int row1 = rbase + 16 + colg;
    bool ok0 = row0 < M, ok1 = row1 < M;
    int rc0 = ok0 ? row0 : M - 1;
    int rc1 = ok1 ? row1 : M - 1;
    const unsigned short* pah0 = Ah + (size_t)b * A_bs + (size_t)rc0 * K + kg * 8;
    const unsigned short* pal0 = Al + (size_t)b * A_bs + (size_t)rc0 * K + kg * 8;
    const unsigned short* pah1 = Ah + (size_t)b * A_bs + (size_t)rc1 * K + kg * 8;
    const unsigned short* pal1 = Al + (size_t)b * A_bs + (size_t)rc1 * K + kg * 8;

    bf16x8 fah[2][KSTEPS], fal[2][KSTEPS];
    bf16x8 whA[KSTEPS], wlA[KSTEPS], whB[KSTEPS], wlB[KSTEPS];
    constexpr int NACC = (KCHUNKS > 1) ? NFRAG : 2;
    f32x4 acc[NACC][2];
#pragma unroll
    for (int i = 0; i < NACC; i++) {
        acc[i][0] = (f32x4){0.f, 0.f, 0.f, 0.f};
        acc[i][1] = (f32x4){0.f, 0.f, 0.f, 0.f};
    }

    auto loadW = [&](bf16x8* wh, bf16x8* wl, int nf, int kc) {
        const unsigned short* ph = Wth + (size_t)(woff + nf * 16 + colg) * K + kc * (KSTEPS * 32) + kg * 8;
        const unsigned short* pl = Wtl + (size_t)(woff + nf * 16 + colg) * K + kc * (KSTEPS * 32) + kg * 8;
#pragma unroll
        for (int ks = 0; ks < KSTEPS; ks++) {
            wh[ks] = *(const bf16x8*)(ph + ks * 32);
            wl[ks] = *(const bf16x8*)(pl + ks * 32);
        }
    };
    auto mm = [&](bf16x8* wh, bf16x8* wl, f32x4& c0, f32x4& c1) {
#pragma unroll
        for (int ks = 0; ks < KSTEPS; ks++) {
            c0 = __builtin_amdgcn_mfma_f32_16x16x32_bf16(wh[ks], fah[0][ks], c0, 0, 0, 0);
            c1 = __builtin_amdgcn_mfma_f32_16x16x32_bf16(wh[ks], fah[1][ks], c1, 0, 0, 0);
            c0 = __builtin_amdgcn_mfma_f32_16x16x32_bf16(wl[ks], fah[0][ks], c0, 0, 0, 0);
            c1 = __builtin_amdgcn_mfma_f32_16x16x32_bf16(wl[ks], fah[1][ks], c1, 0, 0, 0);
            c0 = __builtin_amdgcn_mfma_f32_16x16x32_bf16(wh[ks], fal[0][ks], c0, 0, 0, 0);
            c1 = __builtin_amdgcn_mfma_f32_16x16x32_bf16(wh[ks], fal[1][ks], c1, 0, 0, 0);
        }
    };
    // epilogue -> LDS (swizzled), per nf & mf
    auto epi = [&](f32x4 a, int nf, int mf) {
        int rl = w * 32 + mf * 16 + colg;    // row within block tile
        int c0 = woff + nf * 16 + kg * 4;
        float v[4] = {a[0], a[1], a[2], a[3]};
        if (bias) {
            float4 bv = *(const float4*)&bias[c0];
            v[0] += bv.x; v[1] += bv.y; v[2] += bv.z; v[3] += bv.w;
        }
        if (RELU) {
#pragma unroll
            for (int j = 0; j < 4; j++) v[j] = fmaxf(v[j], 0.f);
        }
        int wc = nf * 8 + kg * 2;
        int wcs = wc ^ ((rl & 7) << 2);      // bank-spread, keeps uint2 contiguity
        union { unsigned short u[4]; unsigned int q[2]; } qh, ql;
#pragma unroll
        for (int j = 0; j < 4; j++) {
            qh.u[j] = f2bf(v[j]);
            if (OUT_MODE == 1) ql.u[j] = f2bf(v[j] - bf2f(qh.u[j]));
        }
        ldsH[rl * WPR + wcs] = qh.q[0];
        ldsH[rl * WPR + wcs + 1] = qh.q[1];
        if (OUT_MODE == 1) {
            ldsL[rl * WPR + wcs] = ql.q[0];
            ldsL[rl * WPR + wcs + 1] = ql.q[1];
        }
    };

#pragma unroll
    for (int kc = 0; kc < KCHUNKS; kc++) {
#pragma unroll
        for (int ks = 0; ks < KSTEPS; ks++) {
            fah[0][ks] = *(const bf16x8*)(pah0 + kc * (KSTEPS * 32) + ks * 32);
            fal[0][ks] = *(const bf16x8*)(pal0 + kc * (KSTEPS * 32) + ks * 32);
            fah[1][ks] = *(const bf16x8*)(pah1 + kc * (KSTEPS * 32) + ks * 32);
            fal[1][ks] = *(const bf16x8*)(pal1 + kc * (KSTEPS * 32) + ks * 32);
        }
        loadW(whA, wlA, 0, kc);
#pragma unroll
        for (int nf = 0; nf < NFRAG; nf += 2) {
            loadW(whB, wlB, nf + 1, kc);
            if constexpr (KCHUNKS > 1) {
                mm(whA, wlA, acc[nf][0], acc[nf][1]);
            } else {
                f32x4 a0 = (f32x4){0.f, 0.f, 0.f, 0.f};
                f32x4 a1 = (f32x4){0.f, 0.f, 0.f, 0.f};
                mm(whA, wlA, a0, a1);
                epi(a0, nf, 0);
                epi(a1, nf, 1);
            }
            if (nf + 2 < NFRAG) loadW(whA, wlA, nf + 2, kc);
            if constexpr (KCHUNKS > 1) {
                mm(whB, wlB, acc[nf + 1][0], acc[nf + 1][1]);
            } else {
                f32x4 a0 = (f32x4){0.f, 0.f, 0.f, 0.f};
                f32x4 a1 = (f32x4){0.f, 0.f, 0.f, 0.f};
                mm(whB, wlB, a0, a1);
                epi(a0, nf + 1, 0);
                epi(a1, nf + 1, 1);
            }
        }
    }
    if constexpr (KCHUNKS > 1) {
#pragma unroll
        for (int nf = 0; nf < NFRAG; nf++) {
            epi(acc[nf][0], nf, 0);
            epi(acc[nf][1], nf, 1);
        }
    }

    // coalesced writeback
    __syncthreads();
    constexpr int U4PR = WPR / 4;            // uint4 per row
    constexpr int NU4 = 128 * U4PR;
    int t = threadIdx.x;
    int rblk = blockIdx.x * 128;
#pragma unroll
    for (int i = 0; i < NU4 / 256; i++) {
        int idx = t + 256 * i;
        int row = idx / U4PR;
        int wc4 = (idx % U4PR) * 4;
        int swz = wc4 ^ ((row & 7) << 2);
        int grow = rblk + row;
        if (grow < M) {
            size_t ci = (size_t)b * C_bs + (size_t)grow * ncTot + woff + wc4 * 2;
            uint4 v = *(const uint4*)&ldsH[row * WPR + swz];
            *(uint4*)((unsigned short*)C1 + ci) = v;
            if constexpr (OUT_MODE == 1) {
                uint4 v2 = *(const uint4*)&ldsL[row * WPR + swz];
                *(uint4*)((unsigned short*)C2 + ci) = v2;
            }
        }
    }
}

// ---------------- host ----------------

extern "C" void kernel_launch(void* const* d_in, const int* in_sizes, int n_in,
                              void* d_out, int out_size, void* d_ws, size_t ws_size,
                              hipStream_t stream) {
    const float* features = (const float*)d_in[0];  // [B,N,128]
    const int* src = (const int*)d_in[1];           // [B,E]
    const int* dst = (const int*)d_in[2];           // [B,E]
    const float* W1 = (const float*)d_in[3];        // [128,256]
    const float* b1 = (const float*)d_in[4];        // [256]
    const float* W2 = (const float*)d_in[5];        // [256,128]
    const float* b2 = (const float*)d_in[6];        // [128]
    float* out = (float*)d_out;                     // [B,N,128]

    const int B = 4;
    const int N = NN;
    const int E = in_sizes[1] / B;

    auto need = [&](int nb) -> size_t {
        size_t bf = ((size_t)nb * N * (128 + 128 * 2 + 256 * 2 + 128)) * sizeof(unsigned short);
        size_t wt = 4 * 32768 * sizeof(unsigned short);
        size_t ints = (size_t)nb * ((size_t)(N + 1) + N) * sizeof(int)
                    + (size_t)nb * E * sizeof(unsigned short);
        return bf + wt + ints + 256;
    };
    int nb = (ws_size >= need(4)) ? 4 : 1;
    int npass = B / nb;
    int xg = 8 / nb;

    char* p = (char*)d_ws;
    unsigned short* fb  = (unsigned short*)p; p += (size_t)nb * N * 128 * sizeof(unsigned short);
    unsigned short* A1h = (unsigned short*)p; p += (size_t)nb * N * 128 * sizeof(unsigned short);
    unsigned short* A1l = (unsigned short*)p; p += (size_t)nb * N * 128 * sizeof(unsigned short);
    unsigned short* Hh  = (unsigned short*)p; p += (size_t)nb * N * 256 * sizeof(unsigned short);
    unsigned short* Hl  = (unsigned short*)p; p += (size_t)nb * N * 256 * sizeof(unsigned short);
    unsigned short* H2b = (unsigned short*)p; p += (size_t)nb * N * 128 * sizeof(unsigned short);
    unsigned short* Wt1h = (unsigned short*)p; p += 32768 * sizeof(unsigned short);
    unsigned short* Wt1l = (unsigned short*)p; p += 32768 * sizeof(unsigned short);
    unsigned short* Wt2h = (unsigned short*)p; p += 32768 * sizeof(unsigned short);
    unsigned short* Wt2l = (unsigned short*)p; p += 32768 * sizeof(unsigned short);
    int* offs = (int*)p;  p += (size_t)nb * (N + 1) * sizeof(int);
    int* curs = (int*)p;  p += (size_t)nb * N * sizeof(int);
    unsigned short* elist = (unsigned short*)p;

    k_prep_w<<<128, 256, 0, stream>>>(W1, W2, Wt1h, Wt1l, Wt2h, Wt2l);

    const int nbx = (N + 31) / 32;                 // node-blocks per pass
    const int jpbE = (E + 255) / 256;              // edge chunks per batch
    dim3 gEdge(8 * ((jpbE + xg - 1) / xg), 1, 1);
    dim3 gAgg(8 * ((2 * nbx + xg - 1) / xg), 1, 1);

    for (int pass = 0; pass < npass; pass++) {
        int b0 = pass * nb;
        const float* feat_p = features + (size_t)b0 * N * 128;
        const int* src_p = src + (size_t)b0 * E;
        const int* dst_p = dst + (size_t)b0 * E;
        float* out_p = out + (size_t)b0 * N * 128;

        hipMemsetAsync(curs, 0, (size_t)nb * N * sizeof(int), stream);

        // features -> bf16 (streaming)
        long n8 = (long)nb * N * 128 / 8;
        k_tobf<<<(int)((n8 + 255) / 256), 256, 0, stream>>>(feat_p, fb, n8);

        k_count<<<gEdge, 256, 0, stream>>>(dst_p, E, curs, N, E, nb, jpbE);
        k_scan<<<dim3(1, 1, nb), 1024, 0, stream>>>(curs, N, offs, N + 1, curs, N, N);
        k_fill<<<gEdge, 256, 0, stream>>>(src_p, E, dst_p, E, curs, N, elist, E, E, nb, jpbE);

        // conv1 aggregation (bf16 gather) -> split bf16 (A1h, A1l)
        k_agg<true><<<gAgg, 256, 0, stream>>>(fb, (long)N * 128, offs, N + 1,
                                              elist, E, nullptr, A1h, A1l, (long)N * 128,
                                              N, nb, nbx);
        // conv1 linear + bias + relu -> split bf16 (Hh, Hl); y splits 256 cols in 2
        k_lin<4, 8, 1, true, 1><<<dim3((N + 127) / 128, 2, nb), 256, 0, stream>>>(
            A1h, A1l, (long)N * 128, Wt1h, Wt1l, b1, Hh, Hl, (long)N * 256, N, 256);
        // conv2 linear (agg commutes): H2b = bf16(H @ W2); y splits 128 cols in 2
        k_lin<4, 4, 2, false, 2><<<dim3((N + 127) / 128, 2, nb), 256, 0, stream>>>(
            Hh, Hl, (long)N * 256, Wt2h, Wt2l, nullptr, H2b, nullptr, (long)N * 128, N, 128);
        // conv2 aggregation (bf16 gather) + bias: out = segsum(H2b[src] -> dst) + b2
        k_agg<false><<<gAgg, 256, 0, stream>>>(H2b, (long)N * 128, offs, N + 1,
                                               elist, E, b2, out_p, nullptr, (long)N * 128,
                                               N, nb, nbx);
    }
}

// Round 10
// 369.988 us; speedup vs baseline: 1.6342x; 1.0360x over previous
//
#include <hip/hip_runtime.h>

#define NN 20000   // nodes per graph

typedef __attribute__((ext_vector_type(8))) __bf16 bf16x8;
typedef __attribute__((ext_vector_type(8))) unsigned short ushort8;
typedef __attribute__((ext_vector_type(4))) float f32x4;

__device__ __forceinline__ unsigned short f2bf(float f) {
    unsigned u = __builtin_bit_cast(unsigned, f);
    u += 0x7fff + ((u >> 16) & 1);   // round-to-nearest-even
    return (unsigned short)(u >> 16);
}
__device__ __forceinline__ float bf2f(unsigned short h) {
    unsigned u = ((unsigned)h) << 16;
    return __builtin_bit_cast(float, u);
}

// ---------------- fp32 -> bf16 streaming convert ----------------

__global__ void k_tobf(const float* __restrict__ in, unsigned short* __restrict__ outp,
                       long n8) {
    long i = (long)blockIdx.x * 256 + threadIdx.x;
    if (i >= n8) return;
    const float4* s = (const float4*)(in + i * 8);
    float4 v0 = s[0], v1 = s[1];
    ushort8 r;
    r[0] = f2bf(v0.x); r[1] = f2bf(v0.y); r[2] = f2bf(v0.z); r[3] = f2bf(v0.w);
    r[4] = f2bf(v1.x); r[5] = f2bf(v1.y); r[6] = f2bf(v1.z); r[7] = f2bf(v1.w);
    *(ushort8*)(outp + i * 8) = r;
}

// ---------------- CSR build (XCD-affine: batch = (gid&7)%nb) ----------------

__global__ void k_count(const int* __restrict__ dst, long dst_bs,
                        int* __restrict__ counts, long cnt_bs, int E, int nb, int jpb) {
    int gid = blockIdx.x;
    int xcd = gid & 7;
    int b = xcd % nb;
    int xg = 8 / nb;
    int jj = (gid >> 3) * xg + (xcd / nb);
    if (jj >= jpb) return;
    int e = jj * 256 + threadIdx.x;
    if (e < E)
        atomicAdd(&counts[(size_t)b * cnt_bs + dst[(size_t)b * dst_bs + e]], 1);
}

// one 1024-thread block per batch: exclusive scan of counts -> offs, cursor
__global__ void k_scan(const int* __restrict__ counts, long cnt_bs,
                       int* __restrict__ offs, long off_bs,
                       int* __restrict__ cursor, long cur_bs, int n) {
    int b = blockIdx.z;
    const int* cnt = counts + (size_t)b * cnt_bs;
    int* off = offs + (size_t)b * off_bs;
    int* cur = cursor + (size_t)b * cur_bs;
    __shared__ int sums[1024];
    int t = threadIdx.x;
    int chunk = (n + 1023) / 1024;
    int lo = t * chunk;
    int hi = min(lo + chunk, n);
    int s = 0;
    for (int i = lo; i < hi; i++) s += cnt[i];
    sums[t] = s;
    __syncthreads();
    for (int d2 = 1; d2 < 1024; d2 <<= 1) {
        int x = (t >= d2) ? sums[t - d2] : 0;
        __syncthreads();
        sums[t] += x;
        __syncthreads();
    }
    if (t == 1023) off[n] = sums[1023];
    int run = sums[t] - s;
    for (int i = lo; i < hi; i++) {
        int c = cnt[i];
        off[i] = run;
        cur[i] = run;
        run += c;
    }
}

__global__ void k_fill(const int* __restrict__ src, long src_bs,
                       const int* __restrict__ dst, long dst_bs,
                       int* __restrict__ cursor, long cur_bs,
                       unsigned short* __restrict__ elist, long el_bs,
                       int E, int nb, int jpb) {
    int gid = blockIdx.x;
    int xcd = gid & 7;
    int b = xcd % nb;
    int xg = 8 / nb;
    int jj = (gid >> 3) * xg + (xcd / nb);
    if (jj >= jpb) return;
    int e = jj * 256 + threadIdx.x;
    if (e < E) {
        int d = dst[(size_t)b * dst_bs + e];
        int s = src[(size_t)b * src_bs + e];
        int p = atomicAdd(&cursor[(size_t)b * cur_bs + d], 1);
        elist[(size_t)b * el_bs + p] = (unsigned short)s;
    }
}

// ---------------- bf16 aggregation: 64-col strips, XCD-affine batches ----------------

template <bool SPLIT>
__global__ void k_agg(const unsigned short* __restrict__ feat, long feat_bs,
                      const int* __restrict__ offs, long off_bs,
                      const unsigned short* __restrict__ elist, long el_bs,
                      const float* __restrict__ bias,   // nullable
                      void* __restrict__ o1, void* __restrict__ o2,
                      long out_bs, int N, int nb, int nbx) {
    int gid = blockIdx.x;
    int xcd = gid & 7;
    int b = xcd % nb;
    int xg = 8 / nb;
    int jj = (gid >> 3) * xg + (xcd / nb);
    if (jj >= 2 * nbx) return;
    int pass = (jj >= nbx) ? 1 : 0;
    int nbk = jj - pass * nbx;
    int g = threadIdx.x >> 3;        // 32 node-groups per block
    int lane = threadIdx.x & 7;
    int n = nbk * 32 + g;
    if (n >= N) return;
    int col0 = pass * 64 + lane * 8;
    const unsigned short* fp = feat + (size_t)b * feat_bs + col0;
    const int* off = offs + (size_t)b * off_bs;
    const unsigned short* el = elist + (size_t)b * el_bs;
    int lo = off[n], hi = off[n + 1];
    float a0[8] = {}, a1[8] = {}, a2[8] = {}, a3[8] = {};
    auto acc = [&](float* a, ushort8 v) {
#pragma unroll
        for (int i = 0; i < 8; i++) a[i] += bf2f(v[i]);
    };
    int e = lo;
    for (; e < hi && (e & 3); e++)
        acc(a0, *(const ushort8*)&fp[(size_t)el[e] * 128]);
    for (; e + 4 <= hi; e += 4) {
        ushort4 idx = *(const ushort4*)&el[e];
        ushort8 v0 = *(const ushort8*)&fp[(size_t)idx.x * 128];
        ushort8 v1 = *(const ushort8*)&fp[(size_t)idx.y * 128];
        ushort8 v2 = *(const ushort8*)&fp[(size_t)idx.z * 128];
        ushort8 v3 = *(const ushort8*)&fp[(size_t)idx.w * 128];
        acc(a0, v0); acc(a1, v1); acc(a2, v2); acc(a3, v3);
    }
    for (; e < hi; e++)
        acc(a0, *(const ushort8*)&fp[(size_t)el[e] * 128]);
    float r[8];
#pragma unroll
    for (int i = 0; i < 8; i++) r[i] = (a0[i] + a1[i]) + (a2[i] + a3[i]);
    size_t oi = (size_t)b * out_bs + (size_t)n * 128 + col0;
    if (SPLIT) {
        ushort8 qh, ql;
#pragma unroll
        for (int i = 0; i < 8; i++) {
            qh[i] = f2bf(r[i]);
            ql[i] = f2bf(r[i] - bf2f(qh[i]));
        }
        *(ushort8*)((unsigned short*)o1 + oi) = qh;
        *(ushort8*)((unsigned short*)o2 + oi) = ql;
    } else {
        float* op = (float*)o1 + oi;
        const float* bp = bias + col0;
#pragma unroll
        for (int i = 0; i < 8; i++) r[i] += bp[i];
        *(float4*)(op) = make_float4(r[0], r[1], r[2], r[3]);
        *(float4*)(op + 4) = make_float4(r[4], r[5], r[6], r[7]);
    }
}

// ---------------- W prep: fp32 [K][N] -> transposed split bf16 [N][K] ----------------

__global__ void k_prep_w(const float* __restrict__ W1, const float* __restrict__ W2,
                         unsigned short* __restrict__ Wt1h, unsigned short* __restrict__ Wt1l,
                         unsigned short* __restrict__ Wt2h, unsigned short* __restrict__ Wt2l) {
    int i = blockIdx.x * 256 + threadIdx.x;
    if (i < 128 * 256) {
        {   // W1 [128][256] -> Wt1 [256][128]
            int k = i / 256, n = i % 256;
            float v = W1[i];
            unsigned short h = f2bf(v);
            Wt1h[n * 128 + k] = h;
            Wt1l[n * 128 + k] = f2bf(v - bf2f(h));
        }
        {   // W2 [256][128] -> Wt2 [128][256]
            int k = i / 128, n = i % 128;
            float v = W2[i];
            unsigned short h = f2bf(v);
            Wt2h[n * 256 + k] = h;
            Wt2l[n * 256 + k] = f2bf(v - bf2f(h));
        }
    }
}

// ---------------- split-bf16 MFMA GEMM, register-resident (launch_bounds 4 w/EU) ------
// OUT_MODE: 1 = split bf16 (hi/lo), 2 = single bf16. LDS-staged coalesced epilogue.
// DBUF: double-buffer W fragments (use when per-chunk footprint is small).

template <int KSTEPS, int NFRAG, int KCHUNKS, bool RELU, int OUT_MODE, bool DBUF>
__launch_bounds__(256, 4)
__global__ void k_lin(const unsigned short* __restrict__ Ah,
                      const unsigned short* __restrict__ Al, long A_bs,
                      const unsigned short* __restrict__ Wth,
                      const unsigned short* __restrict__ Wtl,
                      const float* __restrict__ bias,   // nullable
                      void* __restrict__ C1, void* __restrict__ C2, long C_bs,
                      int M, int ncTot) {
    constexpr int K = KSTEPS * 32 * KCHUNKS;
    constexpr int WPR = NFRAG * 8;           // LDS words per row of the col-slice
    __shared__ unsigned int ldsH[128 * WPR];
    __shared__ unsigned int ldsL[(OUT_MODE == 1) ? 128 * WPR : 4];
    int b = blockIdx.z;
    int woff = blockIdx.y * (NFRAG * 16);
    int w = threadIdx.x >> 6, lane = threadIdx.x & 63;
    int colg = lane & 15, kg = lane >> 4;
    int rbase = blockIdx.x * 128 + w * 32;
    int row0 = rbase + colg;
    int row1 = rbase + 16 + colg;
    bool ok0 = row0 < M, ok1 = row1 < M;
    int rc0 = ok0 ? row0 : M - 1;
    int rc1 = ok1 ? row1 : M - 1;
    const unsigned short* pah0 = Ah + (size_t)b * A_bs + (size_t)rc0 * K + kg * 8;
    const unsigned short* pal0 = Al + (size_t)b * A_bs + (size_t)rc0 * K + kg * 8;
    const unsigned short* pah1 = Ah + (size_t)b * A_bs + (size_t)rc1 * K + kg * 8;
    const unsigned short* pal1 = Al + (size_t)b * A_bs + (size_t)rc1 * K + kg * 8;

    bf16x8 fah[2][KSTEPS], fal[2][KSTEPS];
    bf16x8 whA[KSTEPS], wlA[KSTEPS], whB[KSTEPS], wlB[KSTEPS];
    constexpr int NACC = (KCHUNKS > 1) ? NFRAG : 2;
    f32x4 acc[NACC][2];
#pragma unroll
    for (int i = 0; i < NACC; i++) {
        acc[i][0] = (f32x4){0.f, 0.f, 0.f, 0.f};
        acc[i][1] = (f32x4){0.f, 0.f, 0.f, 0.f};
    }

    auto loadW = [&](bf16x8* wh, bf16x8* wl, int nf, int kc) {
        const unsigned short* ph = Wth + (size_t)(woff + nf * 16 + colg) * K + kc * (KSTEPS * 32) + kg * 8;
        const unsigned short* pl = Wtl + (size_t)(woff + nf * 16 + colg) * K + kc * (KSTEPS * 32) + kg * 8;
#pragma unroll
        for (int ks = 0; ks < KSTEPS; ks++) {
            wh[ks] = *(const bf16x8*)(ph + ks * 32);
            wl[ks] = *(const bf16x8*)(pl + ks * 32);
        }
    };
    auto mm = [&](bf16x8* wh, bf16x8* wl, f32x4& c0, f32x4& c1) {
#pragma unroll
        for (int ks = 0; ks < KSTEPS; ks++) {
            c0 = __builtin_amdgcn_mfma_f32_16x16x32_bf16(wh[ks], fah[0][ks], c0, 0, 0, 0);
            c1 = __builtin_amdgcn_mfma_f32_16x16x32_bf16(wh[ks], fah[1][ks], c1, 0, 0, 0);
            c0 = __builtin_amdgcn_mfma_f32_16x16x32_bf16(wl[ks], fah[0][ks], c0, 0, 0, 0);
            c1 = __builtin_amdgcn_mfma_f32_16x16x32_bf16(wl[ks], fah[1][ks], c1, 0, 0, 0);
            c0 = __builtin_amdgcn_mfma_f32_16x16x32_bf16(wh[ks], fal[0][ks], c0, 0, 0, 0);
            c1 = __builtin_amdgcn_mfma_f32_16x16x32_bf16(wh[ks], fal[1][ks], c1, 0, 0, 0);
        }
    };
    // epilogue -> LDS (swizzled), per nf & mf
    auto epi = [&](f32x4 a, int nf, int mf) {
        int rl = w * 32 + mf * 16 + colg;    // row within block tile
        int c0 = woff + nf * 16 + kg * 4;
        float v[4] = {a[0], a[1], a[2], a[3]};
        if (bias) {
            float4 bv = *(const float4*)&bias[c0];
            v[0] += bv.x; v[1] += bv.y; v[2] += bv.z; v[3] += bv.w;
        }
        if (RELU) {
#pragma unroll
            for (int j = 0; j < 4; j++) v[j] = fmaxf(v[j], 0.f);
        }
        int wc = nf * 8 + kg * 2;
        int wcs = wc ^ (((rl & 7) << 3) & (WPR - 1));   // bank-spread, uint2-contiguous
        union { unsigned short u[4]; unsigned int q[2]; } qh, ql;
#pragma unroll
        for (int j = 0; j < 4; j++) {
            qh.u[j] = f2bf(v[j]);
            if (OUT_MODE == 1) ql.u[j] = f2bf(v[j] - bf2f(qh.u[j]));
        }
        ldsH[rl * WPR + wcs] = qh.q[0];
        ldsH[rl * WPR + wcs + 1] = qh.q[1];
        if (OUT_MODE == 1) {
            ldsL[rl * WPR + wcs] = ql.q[0];
            ldsL[rl * WPR + wcs + 1] = ql.q[1];
        }
    };
    auto step = [&](bf16x8* wh, bf16x8* wl, int nf) {
        if constexpr (KCHUNKS > 1) {
            mm(wh, wl, acc[nf][0], acc[nf][1]);
        } else {
            f32x4 a0 = (f32x4){0.f, 0.f, 0.f, 0.f};
            f32x4 a1 = (f32x4){0.f, 0.f, 0.f, 0.f};
            mm(wh, wl, a0, a1);
            epi(a0, nf, 0);
            epi(a1, nf, 1);
        }
    };

#pragma unroll
    for (int kc = 0; kc < KCHUNKS; kc++) {
#pragma unroll
        for (int ks = 0; ks < KSTEPS; ks++) {
            fah[0][ks] = *(const bf16x8*)(pah0 + kc * (KSTEPS * 32) + ks * 32);
            fal[0][ks] = *(const bf16x8*)(pal0 + kc * (KSTEPS * 32) + ks * 32);
            fah[1][ks] = *(const bf16x8*)(pah1 + kc * (KSTEPS * 32) + ks * 32);
            fal[1][ks] = *(const bf16x8*)(pal1 + kc * (KSTEPS * 32) + ks * 32);
        }
        if constexpr (DBUF) {
            loadW(whA, wlA, 0, kc);
#pragma unroll
            for (int nf = 0; nf < NFRAG; nf += 2) {
                loadW(whB, wlB, nf + 1, kc);
                step(whA, wlA, nf);
                if (nf + 2 < NFRAG) loadW(whA, wlA, nf + 2, kc);
                step(whB, wlB, nf + 1);
            }
        } else {
#pragma unroll
            for (int nf = 0; nf < NFRAG; nf++) {
                loadW(whA, wlA, nf, kc);
                step(whA, wlA, nf);
            }
        }
    }
    if constexpr (KCHUNKS > 1) {
#pragma unroll
        for (int nf = 0; nf < NFRAG; nf++) {
            epi(acc[nf][0], nf, 0);
            epi(acc[nf][1], nf, 1);
        }
    }

    // coalesced writeback
    __syncthreads();
    constexpr int U4PR = WPR / 4;            // uint4 per row
    constexpr int NU4 = 128 * U4PR;
    int t = threadIdx.x;
    int rblk = blockIdx.x * 128;
#pragma unroll
    for (int i = 0; i < NU4 / 256; i++) {
        int idx = t + 256 * i;
        int row = idx / U4PR;
        int wc4 = (idx % U4PR) * 4;
        int swz = wc4 ^ (((row & 7) << 3) & (WPR - 1));
        int grow = rblk + row;
        if (grow < M) {
            size_t ci = (size_t)b * C_bs + (size_t)grow * ncTot + woff + wc4 * 2;
            uint4 v = *(const uint4*)&ldsH[row * WPR + swz];
            *(uint4*)((unsigned short*)C1 + ci) = v;
            if constexpr (OUT_MODE == 1) {
                uint4 v2 = *(const uint4*)&ldsL[row * WPR + swz];
                *(uint4*)((unsigned short*)C2 + ci) = v2;
            }
        }
    }
}

// ---------------- host ----------------

extern "C" void kernel_launch(void* const* d_in, const int* in_sizes, int n_in,
                              void* d_out, int out_size, void* d_ws, size_t ws_size,
                              hipStream_t stream) {
    const float* features = (const float*)d_in[0];  // [B,N,128]
    const int* src = (const int*)d_in[1];           // [B,E]
    const int* dst = (const int*)d_in[2];           // [B,E]
    const float* W1 = (const float*)d_in[3];        // [128,256]
    const float* b1 = (const float*)d_in[4];        // [256]
    const float* W2 = (const float*)d_in[5];        // [256,128]
    const float* b2 = (const float*)d_in[6];        // [128]
    float* out = (float*)d_out;                     // [B,N,128]

    const int B = 4;
    const int N = NN;
    const int E = in_sizes[1] / B;

    auto need = [&](int nb) -> size_t {
        size_t bf = ((size_t)nb * N * (128 + 128 * 2 + 256 * 2 + 128)) * sizeof(unsigned short);
        size_t wt = 4 * 32768 * sizeof(unsigned short);
        size_t ints = (size_t)nb * ((size_t)(N + 1) + N) * sizeof(int)
                    + (size_t)nb * E * sizeof(unsigned short);
        return bf + wt + ints + 256;
    };
    int nb = (ws_size >= need(4)) ? 4 : 1;
    int npass = B / nb;
    int xg = 8 / nb;

    char* p = (char*)d_ws;
    unsigned short* fb  = (unsigned short*)p; p += (size_t)nb * N * 128 * sizeof(unsigned short);
    unsigned short* A1h = (unsigned short*)p; p += (size_t)nb * N * 128 * sizeof(unsigned short);
    unsigned short* A1l = (unsigned short*)p; p += (size_t)nb * N * 128 * sizeof(unsigned short);
    unsigned short* Hh  = (unsigned short*)p; p += (size_t)nb * N * 256 * sizeof(unsigned short);
    unsigned short* Hl  = (unsigned short*)p; p += (size_t)nb * N * 256 * sizeof(unsigned short);
    unsigned short* H2b = (unsigned short*)p; p += (size_t)nb * N * 128 * sizeof(unsigned short);
    unsigned short* Wt1h = (unsigned short*)p; p += 32768 * sizeof(unsigned short);
    unsigned short* Wt1l = (unsigned short*)p; p += 32768 * sizeof(unsigned short);
    unsigned short* Wt2h = (unsigned short*)p; p += 32768 * sizeof(unsigned short);
    unsigned short* Wt2l = (unsigned short*)p; p += 32768 * sizeof(unsigned short);
    int* offs = (int*)p;  p += (size_t)nb * (N + 1) * sizeof(int);
    int* curs = (int*)p;  p += (size_t)nb * N * sizeof(int);
    unsigned short* elist = (unsigned short*)p;

    k_prep_w<<<128, 256, 0, stream>>>(W1, W2, Wt1h, Wt1l, Wt2h, Wt2l);

    const int nbx = (N + 31) / 32;                 // node-blocks per pass
    const int jpbE = (E + 255) / 256;              // edge chunks per batch
    dim3 gEdge(8 * ((jpbE + xg - 1) / xg), 1, 1);
    dim3 gAgg(8 * ((2 * nbx + xg - 1) / xg), 1, 1);

    for (int pass = 0; pass < npass; pass++) {
        int b0 = pass * nb;
        const float* feat_p = features + (size_t)b0 * N * 128;
        const int* src_p = src + (size_t)b0 * E;
        const int* dst_p = dst + (size_t)b0 * E;
        float* out_p = out + (size_t)b0 * N * 128;

        hipMemsetAsync(curs, 0, (size_t)nb * N * sizeof(int), stream);

        // features -> bf16 (streaming)
        long n8 = (long)nb * N * 128 / 8;
        k_tobf<<<(int)((n8 + 255) / 256), 256, 0, stream>>>(feat_p, fb, n8);

        k_count<<<gEdge, 256, 0, stream>>>(dst_p, E, curs, N, E, nb, jpbE);
        k_scan<<<dim3(1, 1, nb), 1024, 0, stream>>>(curs, N, offs, N + 1, curs, N, N);
        k_fill<<<gEdge, 256, 0, stream>>>(src_p, E, dst_p, E, curs, N, elist, E, E, nb, jpbE);

        // conv1 aggregation (bf16 gather) -> split bf16 (A1h, A1l)
        k_agg<true><<<gAgg, 256, 0, stream>>>(fb, (long)N * 128, offs, N + 1,
                                              elist, E, nullptr, A1h, A1l, (long)N * 128,
                                              N, nb, nbx);
        // conv1 linear + bias + relu -> split bf16 (Hh, Hl); y splits 256 cols in 2
        k_lin<4, 8, 1, true, 1, false><<<dim3((N + 127) / 128, 2, nb), 256, 0, stream>>>(
            A1h, A1l, (long)N * 128, Wt1h, Wt1l, b1, Hh, Hl, (long)N * 256, N, 256);
        // conv2 linear (agg commutes): H2b = bf16(H @ W2); y splits 128 cols in 2
        k_lin<2, 4, 4, false, 2, true><<<dim3((N + 127) / 128, 2, nb), 256, 0, stream>>>(
            Hh, Hl, (long)N * 256, Wt2h, Wt2l, nullptr, H2b, nullptr, (long)N * 128, N, 128);
        // conv2 aggregation (bf16 gather) + bias: out = segsum(H2b[src] -> dst) + b2
        k_agg<false><<<gAgg, 256, 0, stream>>>(H2b, (long)N * 128, offs, N + 1,
                                               elist, E, b2, out_p, nullptr, (long)N * 128,
                                               N, nb, nbx);
    }
}